// Round 8
// baseline (60064.630 us; speedup 1.0000x reference)
//
#include <hip/hip_runtime.h>

// ---------------- problem constants ----------------
#define D_HH   1024
#define DR1    512
#define DR2    256
#define RTOT   (DR1 + DR2)
#define TSTEPS 8192

// ---------------- fused scan config (R4 protocol, halved WG population) ----
#define NB     32          // WGs per layer (2 layers -> 64 WGs)
#define BS     1024        // threads per WG (16 waves)
#define HA     (D_HH / NB) // 32 h-rows per WG
#define QA     (RTOT / NB) // 24 reservoir rows per WG
#define NROWB  (HA + QA)   // 56 phase-B rows per WG
#define RING   64          // h1 ring depth (layer0 -> layer1)
#define RMASK  (RING - 1)

typedef __attribute__((ext_vector_type(2))) unsigned long long ull2;

__device__ __forceinline__ float dot4f(float4 a, float4 b) {
    return fmaf(a.x, b.x, fmaf(a.y, b.y, fmaf(a.z, b.z, a.w * b.w)));
}

// ---- tagged-value helpers: entry = (tag<<32)|f32bits; all ops sc0+sc1 (L3
// truth — the proven visibility path; sc0-only refuted in R6, replicas in R7).
__device__ __forceinline__ ull2 ld16(const unsigned long long* p) {
    ull2 v;
    asm volatile("global_load_dwordx4 %0, %1, off sc0 sc1\n\ts_waitcnt vmcnt(0)"
                 : "=&v"(v) : "v"(p) : "memory");
    return v;
}
__device__ __forceinline__ void ld16x2(const unsigned long long* p0,
                                       const unsigned long long* p1,
                                       ull2& a, ull2& b) {
    asm volatile("global_load_dwordx4 %0, %2, off sc0 sc1\n\t"
                 "global_load_dwordx4 %1, %3, off sc0 sc1\n\t"
                 "s_waitcnt vmcnt(0)"
                 : "=&v"(a), "=&v"(b) : "v"(p0), "v"(p1) : "memory");
}
__device__ __forceinline__ unsigned long long ld8(const unsigned long long* p) {
    unsigned long long v;
    asm volatile("global_load_dwordx2 %0, %1, off sc0 sc1\n\ts_waitcnt vmcnt(0)"
                 : "=&v"(v) : "v"(p) : "memory");
    return v;
}
__device__ __forceinline__ void st8(unsigned long long* p, int tag, unsigned pay) {
    unsigned long long pv = ((unsigned long long)(unsigned)tag << 32) | pay;
    asm volatile("global_store_dwordx2 %0, %1, off sc0 sc1"
                 :: "v"(p), "v"(pv) : "memory");
}

// Fused dual-layer persistent recurrent scan (R4 protocol, NB=32 x BS=1024).
//   blocks 0..31 = layer 0 (x from global, h1 -> tagged ring)
//   blocks 32..63 = layer 1 (x = h1 from ring, writes out)
//   h[i] of step t -> tag t+1 ; r[j] of step t -> tag t+1 (memset0 = init)
__global__ __launch_bounds__(BS) void crsd_fused(
    const float* __restrict__ x,    // (T, D_HH)
    const float* __restrict__ Wx,   // (L, D_HH, D_HH)
    const float* __restrict__ Wh,   // (L, D_HH, D_HH)
    const float* __restrict__ bias, // (L, D_HH)
    const float* __restrict__ V1,   // (L, D_HH, DR1)
    const float* __restrict__ U1,   // (L, DR1, D_HH)
    const float* __restrict__ V2,   // (L, D_HH, DR2)
    const float* __restrict__ U2,   // (L, DR2, D_HH)
    float* __restrict__ out,        // (T, D_HH)
    unsigned long long* ring,       // RING*D_HH tagged h1
    unsigned long long* h1s,        // D_HH tagged h (layer 0)
    unsigned long long* h2s,        // D_HH tagged h (layer 1)
    unsigned long long* r1s,        // RTOT tagged r (layer 0)
    unsigned long long* r2s,        // RTOT tagged r (layer 1)
    unsigned long long* prog)       // layer-1 progress cell
{
    const int gid = blockIdx.x;
    const int lay = gid >> 5;
    const int g   = gid & (NB - 1);
    const int tid = threadIdx.x;

    const float* wxp = Wx + (size_t)lay * D_HH * D_HH;
    const float* whp = Wh + (size_t)lay * D_HH * D_HH;
    const float* v1p = V1 + (size_t)lay * D_HH * DR1;
    const float* v2p = V2 + (size_t)lay * D_HH * DR2;
    const float* u1p = U1 + (size_t)lay * DR1 * D_HH;
    const float* u2p = U2 + (size_t)lay * DR2 * D_HH;
    const float* bp  = bias + (size_t)lay * D_HH;
    unsigned long long* rst  = lay ? r2s : r1s;
    unsigned long long* hloc = lay ? h2s : h1s;

    __shared__ __align__(16) float r_s[RTOT];
    __shared__ __align__(16) float h_s[D_HH];
    __shared__ __align__(16) float x_s[D_HH];
    __shared__ float zw[HA];

    // ---- phase A role: row rA (32 lanes/row, 32 rows); V rows in VGPRs ----
    const int rA = tid >> 5;        // 0..31
    const int p  = tid & 31;
    const int iA = g * HA + rA;
    float4 wa[6];
    {
        const float4* v1r = (const float4*)(v1p + (size_t)iA * DR1);
#pragma unroll
        for (int k = 0; k < 4; ++k) wa[k] = v1r[p + 32 * k];
        const float4* v2r = (const float4*)(v2p + (size_t)iA * DR2);
#pragma unroll
        for (int k = 0; k < 2; ++k) wa[4 + k] = v2r[p + 32 * k];
    }

    // ---- phase B role: row rB (16 lanes/row, 56 active rows) ----
    const int rB = tid >> 4;        // 0..63 (rows 56..63 idle)
    const int q  = tid & 15;
    const bool isZ = (rB < HA);
    const bool isQ = (rB >= HA) && (rB < NROWB);
    int jG = 0;
    float bi = 0.f;
    const float* brow = whp;
    const float* xrow = whp;
    if (isZ) {
        brow = whp + (size_t)(g * HA + rB) * D_HH;
        xrow = wxp + (size_t)(g * HA + rB) * D_HH;
        bi   = bp[g * HA + rB];
    } else if (isQ) {
        jG = g * QA + (rB - HA);
        brow = (jG < DR1) ? (u1p + (size_t)jG * D_HH)
                          : (u2p + (size_t)(jG - DR1) * D_HH);
    }
    float4 wb[16], wxr[16];
    {
        const float4* br = (const float4*)brow;
        const float4* xr = (const float4*)xrow;
#pragma unroll
        for (int k = 0; k < 16; ++k) { wb[k] = br[q + 16 * k]; wxr[k] = xr[q + 16 * k]; }
    }

    float rloc = 0.f;   // owned reservoir element (isQ && q==0)
    int   l2c  = 0;     // cached layer-1 progress (layer-0 tid0)

    // ---------------- prologue: x_0 and zw(t=0) ----------------
    if (lay == 0) {
        x_s[tid] = x[tid];
    } else if (tid < D_HH / 2) {
        const unsigned long long* px0 = &ring[2 * tid];
        for (;;) {
            ull2 v = ld16(px0);
            if ((int)(v[0] >> 32) >= 1 && (int)(v[1] >> 32) >= 1) {
                *(float2*)&x_s[2 * tid] =
                    make_float2(__uint_as_float((unsigned)v[0]),
                                __uint_as_float((unsigned)v[1]));
                break;
            }
            __builtin_amdgcn_s_sleep(1);
        }
    }
    __syncthreads();
    if (isZ) {
        const float4* x4 = (const float4*)x_s;
        float acc = 0.f;
#pragma unroll
        for (int k = 0; k < 16; ++k) acc += dot4f(wxr[k], x4[q + 16 * k]);
#pragma unroll
        for (int m = 8; m >= 1; m >>= 1) acc += __shfl_xor(acc, m);
        if (q == 0) zw[rB] = bi + acc;   // h_{-1}=0
    }

    // ---------------- main loop ----------------
    for (int t = 0; t < TSTEPS; ++t) {
        // layer-0 ring back-pressure (lazy; margin 4 slots vs RING=64)
        if (lay == 0 && tid == 0 && t - 60 > l2c) {
            for (;;) {
                unsigned long long v = ld8(prog);
                if ((int)(v >> 32) >= t - 60) { l2c = (int)(v >> 32); break; }
                __builtin_amdgcn_s_sleep(1);
            }
        }

        // ---- stage r_{t-1}: 16B per thread, tags >= t ----
        if (tid < RTOT / 2) {
            const unsigned long long* pr = &rst[2 * tid];
            for (;;) {
                ull2 v = ld16(pr);
                if ((int)(v[0] >> 32) >= t && (int)(v[1] >> 32) >= t) {
                    *(float2*)&r_s[2 * tid] =
                        make_float2(__uint_as_float((unsigned)v[0]),
                                    __uint_as_float((unsigned)v[1]));
                    break;
                }
                __builtin_amdgcn_s_sleep(1);
            }
        }
        __syncthreads();

        // ---- phase A: h_t = tanh(zw + V1 r1 + V2 r2) ----
        {
            const float4* r1v = (const float4*)r_s;
            const float4* r2v = (const float4*)(r_s + DR1);
            float acc = dot4f(wa[0], r1v[p]);
            acc += dot4f(wa[1], r1v[p + 32]);
            acc += dot4f(wa[2], r1v[p + 64]);
            acc += dot4f(wa[3], r1v[p + 96]);
            acc += dot4f(wa[4], r2v[p]);
            acc += dot4f(wa[5], r2v[p + 32]);
#pragma unroll
            for (int m = 16; m >= 1; m >>= 1) acc += __shfl_xor(acc, m);
            if (p == 0) {
                float hv = tanhf(zw[rA] + acc);
                unsigned hb = __float_as_uint(hv);
                st8(&hloc[iA], t + 1, hb);           // visibility first
                if (lay == 0) {
                    st8(&ring[(size_t)(t & RMASK) * D_HH + iA], t + 1, hb);
                } else {
                    out[(size_t)t * D_HH + iA] = hv;
                    if (iA == 0) st8(prog, t + 1, 0u);
                }
                h_s[iA] = hv;                        // self-stage own rows
            }
        }

        // layer-0: prefetch x_{t+1} into LDS (off critical path)
        if (lay == 0) {
            const int ti = (t + 1 < TSTEPS) ? t + 1 : TSTEPS - 1;
            x_s[tid] = x[(size_t)ti * D_HH + tid];
        }

        // ---- stage h_t (skip own rows); layer-1 also stages x_{t+1} ----
        if (tid < D_HH / 2) {
            bool dh = ((tid >> 4) == g);   // own 2-entry chunk: self-staged
            const unsigned long long* ph = &hloc[2 * tid];
            if (lay == 0) {
                if (!dh) {
                    for (;;) {
                        ull2 v = ld16(ph);
                        if ((int)(v[0] >> 32) >= t + 1 && (int)(v[1] >> 32) >= t + 1) {
                            *(float2*)&h_s[2 * tid] =
                                make_float2(__uint_as_float((unsigned)v[0]),
                                            __uint_as_float((unsigned)v[1]));
                            break;
                        }
                        __builtin_amdgcn_s_sleep(1);
                    }
                }
            } else {
                const bool needx = (t + 1 < TSTEPS);
                bool dx = !needx;
                const unsigned long long* px =
                    &ring[(size_t)((t + 1) & RMASK) * D_HH + 2 * tid];
                while (!(dh && dx)) {
                    ull2 a, b;
                    ld16x2(ph, px, a, b);
                    if (!dh && (int)(a[0] >> 32) >= t + 1 && (int)(a[1] >> 32) >= t + 1) {
                        *(float2*)&h_s[2 * tid] =
                            make_float2(__uint_as_float((unsigned)a[0]),
                                        __uint_as_float((unsigned)a[1]));
                        dh = true;
                    }
                    if (!dx && (int)(b[0] >> 32) >= t + 2 && (int)(b[1] >> 32) >= t + 2) {
                        *(float2*)&x_s[2 * tid] =
                            make_float2(__uint_as_float((unsigned)b[0]),
                                        __uint_as_float((unsigned)b[1]));
                        dx = true;
                    }
                    if (!(dh && dx)) __builtin_amdgcn_s_sleep(1);
                }
            }
        }
        __syncthreads();

        // ---- phase B: Q rows -> r_t ; Z rows -> zw_{t+1} = b + Wx x_{t+1} + Wh h_t
        if (rB < NROWB) {
            const float4* h4 = (const float4*)h_s;
            float acc = 0.f;
#pragma unroll
            for (int k = 0; k < 16; ++k) acc += dot4f(wb[k], h4[q + 16 * k]);
            if (isZ) {
                const float4* x4 = (const float4*)x_s;
#pragma unroll
                for (int k = 0; k < 16; ++k) acc += dot4f(wxr[k], x4[q + 16 * k]);
            }
#pragma unroll
            for (int m = 8; m >= 1; m >>= 1) acc += __shfl_xor(acc, m);
            if (q == 0) {
                if (isZ) {
                    zw[rB] = bi + acc;
                } else {
                    rloc = 0.9f * rloc + 0.1f * tanhf(acc);
                    st8(&rst[jG], t + 1, __float_as_uint(rloc));
                }
            }
        }
    }
}

extern "C" void kernel_launch(void* const* d_in, const int* in_sizes, int n_in,
                              void* d_out, int out_size, void* d_ws, size_t ws_size,
                              hipStream_t stream)
{
    const float* x  = (const float*)d_in[0];
    const float* Wx = (const float*)d_in[1];
    const float* Wh = (const float*)d_in[2];
    const float* b  = (const float*)d_in[3];
    const float* V1 = (const float*)d_in[4];
    const float* U1 = (const float*)d_in[5];
    const float* V2 = (const float*)d_in[6];
    const float* U2 = (const float*)d_in[7];
    float* out = (float*)d_out;

    unsigned long long* ring = (unsigned long long*)d_ws;          // RING*D_HH
    unsigned long long* h1s  = ring + (size_t)RING * D_HH;         // D_HH
    unsigned long long* h2s  = h1s + D_HH;                         // D_HH
    unsigned long long* r1s  = h2s + D_HH;                         // RTOT
    unsigned long long* r2s  = r1s + RTOT;                         // RTOT
    unsigned long long* prog = r2s + RTOT;                         // 8 (pad)
    const size_t stateB =
        ((size_t)RING * D_HH + 2 * D_HH + 2 * RTOT + 8) * sizeof(unsigned long long);

    hipMemsetAsync(d_ws, 0, stateB, stream);
    crsd_fused<<<dim3(2 * NB), dim3(BS), 0, stream>>>(
        x, Wx, Wh, b, V1, U1, V2, U2, out,
        ring, h1s, h2s, r1s, r2s, prog);
}

// Round 11
// 32609.598 us; speedup vs baseline: 1.8419x; 1.8419x over previous
//
#include <hip/hip_runtime.h>

// ---------------- problem constants ----------------
#define D_HH   1024
#define DR1    512
#define DR2    256
#define RTOT   (DR1 + DR2)
#define TSTEPS 8192

// ---------------- fused scan config (R4-proven shape) ----------------
#define NB     64          // WGs per layer (2 layers -> 128 WGs)
#define BS     512         // threads per WG (8 waves)
#define HA     (D_HH / NB) // 16 h-rows per WG
#define QA     (RTOT / NB) // 12 reservoir rows per WG
#define NROWB  (HA + QA)   // 28 phase-B rows per WG
#define RING   64          // h1 ring depth (layer0 -> layer1)
#define RMASK  (RING - 1)

typedef __attribute__((ext_vector_type(2))) unsigned long long ull2;

__device__ __forceinline__ float dot4f(float4 a, float4 b) {
    return fmaf(a.x, b.x, fmaf(a.y, b.y, fmaf(a.z, b.z, a.w * b.w)));
}

// ---- tagged-value helpers: entry = (tag<<32)|f32bits; sc0 sc1 = L3 truth.
// ld16/ld8 are safe: the checked value is the OUTPUT of the same asm that
// contains the waitcnt (data dependency pins the order).
__device__ __forceinline__ ull2 ld16(const unsigned long long* p) {
    ull2 v;
    asm volatile("global_load_dwordx4 %0, %1, off sc0 sc1\n\ts_waitcnt vmcnt(0)"
                 : "=&v"(v) : "v"(p) : "memory");
    return v;
}
__device__ __forceinline__ unsigned long long ld8(const unsigned long long* p) {
    unsigned long long v;
    asm volatile("global_load_dwordx2 %0, %1, off sc0 sc1\n\ts_waitcnt vmcnt(0)"
                 : "=&v"(v) : "v"(p) : "memory");
    return v;
}
__device__ __forceinline__ void st8(unsigned long long* p, int tag, unsigned pay) {
    unsigned long long pv = ((unsigned long long)(unsigned)tag << 32) | pay;
    asm volatile("global_store_dwordx2 %0, %1, off sc0 sc1"
                 :: "v"(p), "v"(pv) : "memory");
}

// Double-outstanding pipelined poll of two adjacent 8B tagged entries,
// expressed as ONE self-contained asm block (lesson from R9/R10: a value
// written asynchronously by a load must not cross an asm-block boundary —
// regalloc copies at loop back-edges read in-flight registers).
// Fixed physical regs v96..v103 (clobbered):
//   v[96:97]/v[98:99]  = generation A of entry0/entry1 (pay lo, tag hi)
//   v[100:101]/v[102:103] = generation B
// Wave-level accept: all ACTIVE lanes' two tags >= tgt (s_cbranch_vccz).
// Both exits drain vmcnt(0) before leaving (in-flight loads target clobbers).
__device__ __forceinline__ float2 poll_asm(const unsigned long long* p, int tgt) {
    float r0, r1;
    unsigned long long stmp;
    asm volatile(
        "global_load_dwordx2 v[96:97], %[p], off sc0 sc1\n\t"
        "global_load_dwordx2 v[98:99], %[p], off offset:8 sc0 sc1\n\t"
        "global_load_dwordx2 v[100:101], %[p], off sc0 sc1\n\t"
        "global_load_dwordx2 v[102:103], %[p], off offset:8 sc0 sc1\n\t"
        "1:\n\t"
        "s_waitcnt vmcnt(2)\n\t"                  // generation A landed
        "v_cmp_lt_i32 vcc, v97, %[tgt]\n\t"       // lane not-ready (tag0 < tgt)
        "s_mov_b64 %[stmp], vcc\n\t"
        "v_cmp_lt_i32 vcc, v99, %[tgt]\n\t"       // tag1 < tgt
        "s_or_b64 vcc, vcc, %[stmp]\n\t"
        "s_cbranch_vccz 5f\n\t"                   // all active lanes ready -> A
        "global_load_dwordx2 v[96:97], %[p], off sc0 sc1\n\t"
        "global_load_dwordx2 v[98:99], %[p], off offset:8 sc0 sc1\n\t"
        "s_waitcnt vmcnt(2)\n\t"                  // generation B landed
        "v_cmp_lt_i32 vcc, v101, %[tgt]\n\t"
        "s_mov_b64 %[stmp], vcc\n\t"
        "v_cmp_lt_i32 vcc, v103, %[tgt]\n\t"
        "s_or_b64 vcc, vcc, %[stmp]\n\t"
        "s_cbranch_vccz 6f\n\t"                   // all ready -> B
        "global_load_dwordx2 v[100:101], %[p], off sc0 sc1\n\t"
        "global_load_dwordx2 v[102:103], %[p], off offset:8 sc0 sc1\n\t"
        "s_branch 1b\n\t"
        "5:\n\t"
        "s_waitcnt vmcnt(0)\n\t"                  // drain B before regs escape
        "v_mov_b32 %[r0], v96\n\t"
        "v_mov_b32 %[r1], v98\n\t"
        "s_branch 7f\n\t"
        "6:\n\t"
        "s_waitcnt vmcnt(0)\n\t"                  // drain A'
        "v_mov_b32 %[r0], v100\n\t"
        "v_mov_b32 %[r1], v102\n\t"
        "7:\n\t"
        : [r0]"=v"(r0), [r1]"=v"(r1), [stmp]"=&s"(stmp)
        : [p]"v"(p), [tgt]"v"(tgt)
        : "memory", "vcc",
          "v96","v97","v98","v99","v100","v101","v102","v103");
    return make_float2(r0, r1);
}

// Fused dual-layer persistent recurrent scan (R4 structure + asm poll).
//   blocks 0..63 = layer 0 (x from global, h1 -> tagged ring)
//   blocks 64..127 = layer 1 (x = h1 from ring, writes out)
//   h[i] of step t -> tag t+1 ; r[j] of step t -> tag t+1 (memset0 = init)
__global__ __launch_bounds__(BS, 2) void crsd_fused(
    const float* __restrict__ x,    // (T, D_HH)
    const float* __restrict__ Wx,   // (L, D_HH, D_HH)
    const float* __restrict__ Wh,   // (L, D_HH, D_HH)
    const float* __restrict__ bias, // (L, D_HH)
    const float* __restrict__ V1,   // (L, D_HH, DR1)
    const float* __restrict__ U1,   // (L, DR1, D_HH)
    const float* __restrict__ V2,   // (L, D_HH, DR2)
    const float* __restrict__ U2,   // (L, DR2, D_HH)
    float* __restrict__ out,        // (T, D_HH)
    unsigned long long* ring,       // RING*D_HH tagged h1
    unsigned long long* h1s,        // D_HH tagged h (layer 0)
    unsigned long long* h2s,        // D_HH tagged h (layer 1)
    unsigned long long* r1s,        // RTOT tagged r (layer 0)
    unsigned long long* r2s,        // RTOT tagged r (layer 1)
    unsigned long long* prog)       // layer-1 progress cell
{
    const int gid = blockIdx.x;
    const int lay = gid >> 6;
    const int g   = gid & (NB - 1);
    const int tid = threadIdx.x;

    const float* wxp = Wx + (size_t)lay * D_HH * D_HH;
    const float* whp = Wh + (size_t)lay * D_HH * D_HH;
    const float* v1p = V1 + (size_t)lay * D_HH * DR1;
    const float* v2p = V2 + (size_t)lay * D_HH * DR2;
    const float* u1p = U1 + (size_t)lay * DR1 * D_HH;
    const float* u2p = U2 + (size_t)lay * DR2 * D_HH;
    const float* bp  = bias + (size_t)lay * D_HH;
    unsigned long long* rst  = lay ? r2s : r1s;
    unsigned long long* hloc = lay ? h2s : h1s;

    __shared__ __align__(16) float r_s[RTOT];
    __shared__ __align__(16) float h_s[D_HH];
    __shared__ __align__(16) float x_s[D_HH];
    __shared__ float zw[HA];

    // ---- phase A role: row rA (32 lanes/row); V rows in VGPRs (permuted) ----
    const int rA = tid >> 5;
    const int p  = tid & 31;
    const int iA = g * HA + rA;
    float4 wa[6];
    {
        const float4* v1r = (const float4*)(v1p + (size_t)iA * DR1);
#pragma unroll
        for (int k = 0; k < 4; ++k) wa[k] = v1r[p + 32 * k];
        const float4* v2r = (const float4*)(v2p + (size_t)iA * DR2);
#pragma unroll
        for (int k = 0; k < 2; ++k) wa[4 + k] = v2r[p + 32 * k];
    }

    // ---- phase B role: row rB (16 lanes/row); Wh/U + Wx rows in VGPRs ----
    const int rB = tid >> 4;
    const int q  = tid & 15;
    const bool isZ = (rB < HA);
    const bool isQ = (rB >= HA) && (rB < NROWB);
    int jG = 0;
    float bi = 0.f;
    const float* brow = whp;
    const float* xrow = whp;
    if (isZ) {
        brow = whp + (size_t)(g * HA + rB) * D_HH;
        xrow = wxp + (size_t)(g * HA + rB) * D_HH;
        bi   = bp[g * HA + rB];
    } else if (isQ) {
        jG = g * QA + (rB - HA);
        brow = (jG < DR1) ? (u1p + (size_t)jG * D_HH)
                          : (u2p + (size_t)(jG - DR1) * D_HH);
    }
    float4 wb[16], wxr[16];
    {
        const float4* br = (const float4*)brow;
        const float4* xr = (const float4*)xrow;
#pragma unroll
        for (int k = 0; k < 16; ++k) { wb[k] = br[q + 16 * k]; wxr[k] = xr[q + 16 * k]; }
    }

    float rloc = 0.f;   // owned reservoir element (isQ && q==0)
    int   l2c  = 0;     // cached layer-1 progress (layer-0 tid0)

    // ---------------- prologue: x_0 and zw(t=0) ----------------
    if (lay == 0) {
        float2 xv = *(const float2*)&x[2 * tid];
        *(float2*)&x_s[2 * tid] = xv;
    } else {
        const unsigned long long* px0 = &ring[2 * tid];
        for (;;) {
            ull2 v = ld16(px0);
            if ((int)(v[0] >> 32) >= 1 && (int)(v[1] >> 32) >= 1) {
                *(float2*)&x_s[2 * tid] =
                    make_float2(__uint_as_float((unsigned)v[0]),
                                __uint_as_float((unsigned)v[1]));
                break;
            }
            __builtin_amdgcn_s_sleep(1);
        }
    }
    __syncthreads();
    if (isZ) {
        const float4* x4 = (const float4*)x_s;
        float acc = 0.f;
#pragma unroll
        for (int k = 0; k < 16; ++k) acc += dot4f(wxr[k], x4[q + 16 * k]);
#pragma unroll
        for (int m = 8; m >= 1; m >>= 1) acc += __shfl_xor(acc, m);
        if (q == 0) zw[rB] = bi + acc;   // h_{-1}=0
    }

    // ---------------- main loop ----------------
    for (int t = 0; t < TSTEPS; ++t) {
        // layer-0 ring back-pressure (lazy; margin 4 slots vs RING=64)
        if (lay == 0 && tid == 0 && t - 60 > l2c) {
            for (;;) {
                unsigned long long v = ld8(prog);
                if ((int)(v >> 32) >= t - 60) { l2c = (int)(v >> 32); break; }
                __builtin_amdgcn_s_sleep(1);
            }
        }

        // ---- stage r_{t-1}: one 16B pair per thread, pipelined asm poll ----
        if (tid < RTOT / 2) {
            float2 v = poll_asm(&rst[2 * tid], t);
            *(float2*)&r_s[2 * tid] = v;
        }
        __syncthreads();

        // ---- phase A: h_t = tanh(zw + V1 r1 + V2 r2) ----
        {
            const float4* r1v = (const float4*)r_s;
            const float4* r2v = (const float4*)(r_s + DR1);
            float acc = dot4f(wa[0], r1v[p]);
            acc += dot4f(wa[1], r1v[p + 32]);
            acc += dot4f(wa[2], r1v[p + 64]);
            acc += dot4f(wa[3], r1v[p + 96]);
            acc += dot4f(wa[4], r2v[p]);
            acc += dot4f(wa[5], r2v[p + 32]);
#pragma unroll
            for (int m = 16; m >= 1; m >>= 1) acc += __shfl_xor(acc, m);
            if (p == 0) {
                float hv = tanhf(zw[rA] + acc);
                unsigned hb = __float_as_uint(hv);
                st8(&hloc[iA], t + 1, hb);           // visibility first
                if (lay == 0) {
                    st8(&ring[(size_t)(t & RMASK) * D_HH + iA], t + 1, hb);
                } else {
                    out[(size_t)t * D_HH + iA] = hv;
                    if (iA == 0) st8(prog, t + 1, 0u);
                }
                h_s[iA] = hv;                        // self-stage own rows
            }
        }

        // layer-0: prefetch x_{t+1} into LDS (off critical path)
        if (lay == 0) {
            const int ti = (t + 1 < TSTEPS) ? t + 1 : TSTEPS - 1;
            float2 xv = *(const float2*)&x[(size_t)ti * D_HH + 2 * tid];
            *(float2*)&x_s[2 * tid] = xv;
        }

        // layer-1: stage x_{t+1} from ring (data is ~60 steps old; quick check
        // loop OFF the h-poll's iteration period)
        if (lay == 1 && t + 1 < TSTEPS) {
            const unsigned long long* px =
                &ring[(size_t)((t + 1) & RMASK) * D_HH + 2 * tid];
            for (;;) {
                ull2 v = ld16(px);
                if ((int)(v[0] >> 32) >= t + 2 && (int)(v[1] >> 32) >= t + 2) {
                    *(float2*)&x_s[2 * tid] =
                        make_float2(__uint_as_float((unsigned)v[0]),
                                    __uint_as_float((unsigned)v[1]));
                    break;
                }
                __builtin_amdgcn_s_sleep(1);
            }
        }

        // ---- stage h_t: one 16B pair per thread, pipelined; skip own rows ----
        if ((tid >> 3) != g) {
            float2 v = poll_asm(&hloc[2 * tid], t + 1);
            *(float2*)&h_s[2 * tid] = v;
        }
        __syncthreads();

        // ---- phase B: Q rows -> r_t ; Z rows -> zw_{t+1} = b + Wx x_{t+1} + Wh h_t
        if (rB < NROWB) {
            const float4* h4 = (const float4*)h_s;
            float acc = 0.f;
#pragma unroll
            for (int k = 0; k < 16; ++k) acc += dot4f(wb[k], h4[q + 16 * k]);
            if (isZ) {
                const float4* x4 = (const float4*)x_s;
#pragma unroll
                for (int k = 0; k < 16; ++k) acc += dot4f(wxr[k], x4[q + 16 * k]);
            }
#pragma unroll
            for (int m = 8; m >= 1; m >>= 1) acc += __shfl_xor(acc, m);
            if (q == 0) {
                if (isZ) {
                    zw[rB] = bi + acc;
                } else {
                    rloc = 0.9f * rloc + 0.1f * tanhf(acc);
                    st8(&rst[jG], t + 1, __float_as_uint(rloc));
                }
            }
        }
    }
}

extern "C" void kernel_launch(void* const* d_in, const int* in_sizes, int n_in,
                              void* d_out, int out_size, void* d_ws, size_t ws_size,
                              hipStream_t stream)
{
    const float* x  = (const float*)d_in[0];
    const float* Wx = (const float*)d_in[1];
    const float* Wh = (const float*)d_in[2];
    const float* b  = (const float*)d_in[3];
    const float* V1 = (const float*)d_in[4];
    const float* U1 = (const float*)d_in[5];
    const float* V2 = (const float*)d_in[6];
    const float* U2 = (const float*)d_in[7];
    float* out = (float*)d_out;

    unsigned long long* ring = (unsigned long long*)d_ws;          // RING*D_HH
    unsigned long long* h1s  = ring + (size_t)RING * D_HH;         // D_HH
    unsigned long long* h2s  = h1s + D_HH;                         // D_HH
    unsigned long long* r1s  = h2s + D_HH;                         // RTOT
    unsigned long long* r2s  = r1s + RTOT;                         // RTOT
    unsigned long long* prog = r2s + RTOT;                         // 8 (pad)
    const size_t stateB =
        ((size_t)RING * D_HH + 2 * D_HH + 2 * RTOT + 8) * sizeof(unsigned long long);

    hipMemsetAsync(d_ws, 0, stateB, stream);
    crsd_fused<<<dim3(2 * NB), dim3(BS), 0, stream>>>(
        x, Wx, Wh, b, V1, U1, V2, U2, out,
        ring, h1s, h2s, r1s, r2s, prog);
}

// Round 12
// 29628.204 us; speedup vs baseline: 2.0273x; 1.1006x over previous
//
#include <hip/hip_runtime.h>

// ---------------- problem constants ----------------
#define D_HH   1024
#define DR1    512
#define DR2    256
#define RTOT   (DR1 + DR2)
#define TSTEPS 8192
#define LAYERS 2

// ---------------- fused scan config ----------------
#define NB    64          // WGs per layer (2 layers -> 128 WGs total)
#define BS    512         // threads per WG (8 waves)
#define HA    (D_HH / NB) // 16 h-rows owned per WG
#define QA    (RTOT / NB) // 12 reservoir rows per WG
#define NROWB (HA + QA)   // 28 phase-B rows per WG
#define RING  64          // h1 ring depth (steps); tags self-validate slots
#define RMASK (RING - 1)

__device__ __forceinline__ float dot4f(float4 a, float4 b) {
    return fmaf(a.x, b.x, fmaf(a.y, b.y, fmaf(a.z, b.z, a.w * b.w)));
}

__device__ __forceinline__ unsigned long long ldtag(const unsigned long long* p) {
    return __hip_atomic_load(p, __ATOMIC_RELAXED, __HIP_MEMORY_SCOPE_AGENT);
}
__device__ __forceinline__ void sttag(unsigned long long* p, int tag, float v) {
    unsigned long long pv =
        ((unsigned long long)(unsigned)tag << 32) | __float_as_uint(v);
    __hip_atomic_store(p, pv, __ATOMIC_RELAXED, __HIP_MEMORY_SCOPE_AGENT);
}

// Fused dual-layer persistent recurrent scan (the R4-proven kernel).
//   blocks 0..63   = layer 0 (reads x from global, publishes h1 into tagged ring)
//   blocks 64..127 = layer 1 (reads x = h1 from ring, writes final out)
// Exchange = 8B tagged values (tag<<32)|f32bits at agent scope:
//   h[i] of step t  -> tag t+1  (layer0: ring slot t&63; layer1: h2state)
//   r[j] of step t  -> tag t+1  (per-layer rstate; memset0 => r_{-1}=0, tag 0)
// zw for step t+1 (= b + Wx x_{t+1} + Wh h_t) is computed in phase B of step t;
// Wx is applied IN-SCAN (no pre-GEMM).
__global__ __launch_bounds__(BS, 2) void crsd_fused(
    const float* __restrict__ x,    // (T, D_HH) layer-0 input
    const float* __restrict__ Wx,   // (L, D_HH, D_HH)
    const float* __restrict__ Wh,   // (L, D_HH, D_HH)
    const float* __restrict__ bias, // (L, D_HH)
    const float* __restrict__ V1,   // (L, D_HH, DR1)
    const float* __restrict__ U1,   // (L, DR1, D_HH)
    const float* __restrict__ V2,   // (L, D_HH, DR2)
    const float* __restrict__ U2,   // (L, DR2, D_HH)
    float* __restrict__ out,        // (T, D_HH) = layer-1 h sequence
    unsigned long long* ring,       // RING*D_HH tagged h1 (memset 0)
    unsigned long long* h2state,    // D_HH tagged h2 (memset 0)
    unsigned long long* r1state,    // RTOT tagged r (layer 0, memset 0)
    unsigned long long* r2state)    // RTOT tagged r (layer 1, memset 0)
{
    const int gid   = blockIdx.x;
    const int layer = gid >> 6;
    const int g     = gid & (NB - 1);
    const int tid   = threadIdx.x;

    const float* wxp = Wx + (size_t)layer * D_HH * D_HH;
    const float* whp = Wh + (size_t)layer * D_HH * D_HH;
    const float* v1p = V1 + (size_t)layer * D_HH * DR1;
    const float* v2p = V2 + (size_t)layer * D_HH * DR2;
    const float* u1p = U1 + (size_t)layer * DR1 * D_HH;
    const float* u2p = U2 + (size_t)layer * DR2 * D_HH;
    const float* bp  = bias + (size_t)layer * D_HH;
    unsigned long long* rstate = layer ? r2state : r1state;

    __shared__ __align__(16) float r_s[RTOT];
    __shared__ __align__(16) float h_s[D_HH];
    __shared__ __align__(16) float x_s[D_HH];
    __shared__ float zw[HA];

    // ---- phase A role: row rA (32 lanes/row); V rows in VGPRs (permuted) ----
    const int rA = tid >> 5;
    const int p  = tid & 31;
    const int iA = g * HA + rA;
    float4 wa[6];
    {
        const float4* v1r = (const float4*)(v1p + (size_t)iA * DR1);
#pragma unroll
        for (int k = 0; k < 4; ++k) wa[k] = v1r[p + 32 * k];
        const float4* v2r = (const float4*)(v2p + (size_t)iA * DR2);
#pragma unroll
        for (int k = 0; k < 2; ++k) wa[4 + k] = v2r[p + 32 * k];
    }

    // ---- phase B role: row rB (16 lanes/row); Wh/U + Wx rows in VGPRs ----
    const int rB = tid >> 4;
    const int q  = tid & 15;
    const bool isZ = (rB < HA);
    const bool isQ = (rB >= HA) && (rB < NROWB);
    int jG = 0;
    float bi = 0.f;
    const float* brow = whp;           // dummy-safe
    const float* xrow = whp;           // dummy-safe
    if (isZ) {
        brow = whp + (size_t)(g * HA + rB) * D_HH;
        xrow = wxp + (size_t)(g * HA + rB) * D_HH;
        bi   = bp[g * HA + rB];
    } else if (isQ) {
        jG = g * QA + (rB - HA);
        brow = (jG < DR1) ? (u1p + (size_t)jG * D_HH)
                          : (u2p + (size_t)(jG - DR1) * D_HH);
    }
    float4 wb[16], wxr[16];
    {
        const float4* br = (const float4*)brow;
        const float4* xr = (const float4*)xrow;
#pragma unroll
        for (int k = 0; k < 16; ++k) { wb[k] = br[q + 16 * k]; wxr[k] = xr[q + 16 * k]; }
    }

    float rloc = 0.f;        // owned reservoir element (isQ && q==0)
    int   l2c  = 0;          // cached layer-1 progress (layer-0 thread 0 only)

    // ---------------- prologue: stage x_0, compute zw for t=0 ----------------
    if (layer == 0) {
        float2 xv = *(const float2*)&x[2 * tid];
        x_s[2 * tid] = xv.x; x_s[2 * tid + 1] = xv.y;
    } else {
        bool d0 = false, d1 = false;
        while (!(d0 && d1)) {
            unsigned long long v0 = 0, v1 = 0;
            if (!d0) v0 = ldtag(&ring[tid]);
            if (!d1) v1 = ldtag(&ring[tid + BS]);
            if (!d0 && (int)(v0 >> 32) >= 1) { x_s[tid] = __uint_as_float((unsigned)v0); d0 = true; }
            if (!d1 && (int)(v1 >> 32) >= 1) { x_s[tid + BS] = __uint_as_float((unsigned)v1); d1 = true; }
            if (!(d0 && d1)) __builtin_amdgcn_s_sleep(1);
        }
    }
    __syncthreads();
    if (isZ) {
        const float4* x4 = (const float4*)x_s;
        float acc = 0.f;
#pragma unroll
        for (int k = 0; k < 16; ++k) acc += dot4f(wxr[k], x4[q + 16 * k]);
#pragma unroll
        for (int m = 8; m >= 1; m >>= 1) acc += __shfl_xor(acc, m);
        if (q == 0) zw[rB] = bi + acc;   // h_{-1}=0: no Wh term
    }
    // (t=0 r-poll barrier orders zw writes vs phase-A reads)

    for (int t = 0; t < TSTEPS; ++t) {
        // ---- layer-0 ring back-pressure (lazy, thread 0; margin 2 slots) ----
        if (layer == 0 && tid == 0 && t - 60 > l2c) {
            unsigned long long v;
            do { v = ldtag(&h2state[g * HA]); } while ((int)(v >> 32) < t - 60);
            l2c = (int)(v >> 32);
        }

        // ---- stage r_{t-1}: dual-outstanding poll, tags >= t ----
        {
            const bool has1 = (tid < (RTOT - BS));   // tid < 256
            bool d0 = false, d1 = !has1;
            while (!(d0 && d1)) {
                unsigned long long v0 = 0, v1 = 0;
                if (!d0) v0 = ldtag(&rstate[tid]);
                if (!d1) v1 = ldtag(&rstate[tid + BS]);
                if (!d0 && (int)(v0 >> 32) >= t) { r_s[tid] = __uint_as_float((unsigned)v0); d0 = true; }
                if (!d1 && (int)(v1 >> 32) >= t) { r_s[tid + BS] = __uint_as_float((unsigned)v1); d1 = true; }
                if (!(d0 && d1)) __builtin_amdgcn_s_sleep(1);
            }
        }
        __syncthreads();

        // ---- phase A: h_t = tanh(zw + V1 r1 + V2 r2) ----
        unsigned long long* hdst = layer ? h2state
                                         : (ring + (size_t)(t & RMASK) * D_HH);
        {
            const float4* r1v = (const float4*)r_s;
            const float4* r2v = (const float4*)(r_s + DR1);
            float acc = dot4f(wa[0], r1v[p]);
            acc += dot4f(wa[1], r1v[p + 32]);
            acc += dot4f(wa[2], r1v[p + 64]);
            acc += dot4f(wa[3], r1v[p + 96]);
            acc += dot4f(wa[4], r2v[p]);
            acc += dot4f(wa[5], r2v[p + 32]);
#pragma unroll
            for (int m = 16; m >= 1; m >>= 1) acc += __shfl_xor(acc, m);
            if (p == 0) {
                float hv = tanhf(zw[rA] + acc);
                sttag(&hdst[iA], t + 1, hv);     // visibility first
                h_s[iA] = hv;                    // own entries: self-staged
                if (layer) out[(size_t)t * D_HH + iA] = hv;
            }
        }

        // layer-0: prefetch x_{t+1} (off critical path; clamped at the end)
        float2 xv;
        if (layer == 0) {
            const int ti = (t + 1 < TSTEPS) ? t + 1 : TSTEPS - 1;
            xv = *(const float2*)&x[(size_t)ti * D_HH + 2 * tid];
            x_s[2 * tid] = xv.x; x_s[2 * tid + 1] = xv.y;
        }

        // ---- stage h_t (skip own 16 entries) and, for layer 1, x_{t+1} ----
        {
            const unsigned long long* hsrc = hdst;
            const unsigned long long* xsrc =
                ring + (size_t)((t + 1) & RMASK) * D_HH;
            const bool needx = (layer == 1) && (t + 1 < TSTEPS);
            bool dh0 = ((tid >> 4) == g);
            bool dh1 = (((tid + BS) >> 4) == g);
            bool dx0 = !needx, dx1 = !needx;
            while (!(dh0 && dh1 && dx0 && dx1)) {
                unsigned long long v0 = 0, v1 = 0, w0 = 0, w1 = 0;
                if (!dh0) v0 = ldtag(&hsrc[tid]);
                if (!dh1) v1 = ldtag(&hsrc[tid + BS]);
                if (!dx0) w0 = ldtag(&xsrc[tid]);
                if (!dx1) w1 = ldtag(&xsrc[tid + BS]);
                if (!dh0 && (int)(v0 >> 32) >= t + 1) { h_s[tid] = __uint_as_float((unsigned)v0); dh0 = true; }
                if (!dh1 && (int)(v1 >> 32) >= t + 1) { h_s[tid + BS] = __uint_as_float((unsigned)v1); dh1 = true; }
                if (!dx0 && (int)(w0 >> 32) >= t + 2) { x_s[tid] = __uint_as_float((unsigned)w0); dx0 = true; }
                if (!dx1 && (int)(w1 >> 32) >= t + 2) { x_s[tid + BS] = __uint_as_float((unsigned)w1); dx1 = true; }
                if (!(dh0 && dh1 && dx0 && dx1)) __builtin_amdgcn_s_sleep(1);
            }
        }
        __syncthreads();

        // ---- phase B: Q rows -> r_t; Z rows -> zw_{t+1} = b + Wx x_{t+1} + Wh h_t
        if (rB < NROWB) {
            const float4* h4 = (const float4*)h_s;
            float acc = 0.f;
#pragma unroll
            for (int k = 0; k < 16; ++k) acc += dot4f(wb[k], h4[q + 16 * k]);
            if (isZ) {
                const float4* x4 = (const float4*)x_s;
#pragma unroll
                for (int k = 0; k < 16; ++k) acc += dot4f(wxr[k], x4[q + 16 * k]);
            }
#pragma unroll
            for (int m = 8; m >= 1; m >>= 1) acc += __shfl_xor(acc, m);
            if (q == 0) {
                if (isZ) {
                    zw[rB] = bi + acc;
                } else {
                    rloc = 0.9f * rloc + 0.1f * tanhf(acc);
                    sttag(&rstate[jG], t + 1, rloc);
                }
            }
        }
    }
}

extern "C" void kernel_launch(void* const* d_in, const int* in_sizes, int n_in,
                              void* d_out, int out_size, void* d_ws, size_t ws_size,
                              hipStream_t stream)
{
    const float* x  = (const float*)d_in[0];   // (T, D_HH)
    const float* Wx = (const float*)d_in[1];   // (L, D_HH, D_HH)
    const float* Wh = (const float*)d_in[2];   // (L, D_HH, D_HH)
    const float* b  = (const float*)d_in[3];   // (L, D_HH)
    const float* V1 = (const float*)d_in[4];   // (L, D_HH, DR1)
    const float* U1 = (const float*)d_in[5];   // (L, DR1, D_HH)
    const float* V2 = (const float*)d_in[6];   // (L, D_HH, DR2)
    const float* U2 = (const float*)d_in[7];   // (L, DR2, D_HH)
    float* out = (float*)d_out;                // (T, D_HH)

    unsigned long long* ring    = (unsigned long long*)d_ws;       // RING*D_HH
    unsigned long long* h2state = ring + (size_t)RING * D_HH;      // D_HH
    unsigned long long* r1state = h2state + D_HH;                  // RTOT
    unsigned long long* r2state = r1state + RTOT;                  // RTOT
    const size_t stateB =
        ((size_t)RING * D_HH + D_HH + 2 * RTOT) * sizeof(unsigned long long);

    hipMemsetAsync(d_ws, 0, stateB, stream);
    crsd_fused<<<dim3(2 * NB), dim3(BS), 0, stream>>>(
        x, Wx, Wh, b, V1, U1, V2, U2, out, ring, h2state, r1state, r2state);
}